// Round 2
// baseline (374.908 us; speedup 1.0000x reference)
//
#include <hip/hip_runtime.h>
#include <hip/hip_bf16.h>

#define B_ 8
#define N_ 1024
#define DIN 256
#define DOUT 256
#define R_ 4

typedef __attribute__((ext_vector_type(8))) short bf16x8;
typedef __attribute__((ext_vector_type(4))) float f32x4;
typedef __attribute__((ext_vector_type(4))) int i32x4;

__device__ __forceinline__ unsigned short f2bf(float f) {
    union { float f; unsigned int u; } v; v.f = f;
    unsigned int u = v.u;
    u += 0x7fffu + ((u >> 16) & 1u);
    return (unsigned short)(u >> 16);
}

// ---------------- k0: convert rel_w (R*256*256 f32) to bf16 ----------------
__global__ void k0_cvt_relw(const float* __restrict__ rw,
                            unsigned short* __restrict__ rwb) {
    int t = blockIdx.x * blockDim.x + threadIdx.x;  // 0..65535 (float4 units)
    float4 v = ((const float4*)rw)[t];
    ushort4 o;
    o.x = f2bf(v.x); o.y = f2bf(v.y); o.z = f2bf(v.z); o.w = f2bf(v.w);
    ((ushort4*)rwb)[t] = o;
}

// ---------------- k1: feats^T[b,r,d,n] = (node[b] @ rel_w[r]^T + rel_b)^T ---
// plus fused epilogue: ebf[b,r,n] = bf16(exp(sum_d feats[n][d]*attn_w[256+d]))
// grid 512 = (b,r,nt), 256 threads = 4 waves, wave = 16 rows of n.
__global__ __launch_bounds__(256) void k1_proj(const float* __restrict__ node,
        const unsigned short* __restrict__ rwb, const float* __restrict__ rel_b,
        const float* __restrict__ attn_w,
        unsigned short* __restrict__ featsT, unsigned short* __restrict__ ebf) {
    int bid = blockIdx.x;
    int nt = bid & 15, r = (bid >> 4) & 3, b = bid >> 6;
    int wave = threadIdx.x >> 6, lane = threadIdx.x & 63;
    int m = lane & 15, q = lane >> 4;
    int n0 = nt * 64 + wave * 16;

    const float* Abase = node + ((b * N_ + n0 + m) * DIN) + q * 8;
    const unsigned short* Bbase = rwb + ((r * DOUT + m) * DIN) + q * 8;

    f32x4 acc[16];
#pragma unroll
    for (int i = 0; i < 16; i++) acc[i] = (f32x4)0.0f;

    for (int k = 0; k < DIN; k += 32) {
        float4 a0 = *(const float4*)(Abase + k);
        float4 a1 = *(const float4*)(Abase + k + 4);
        bf16x8 af;
        af[0] = (short)f2bf(a0.x); af[1] = (short)f2bf(a0.y);
        af[2] = (short)f2bf(a0.z); af[3] = (short)f2bf(a0.w);
        af[4] = (short)f2bf(a1.x); af[5] = (short)f2bf(a1.y);
        af[6] = (short)f2bf(a1.z); af[7] = (short)f2bf(a1.w);
#pragma unroll
        for (int nb = 0; nb < 16; nb++) {
            bf16x8 bf = *(const bf16x8*)(Bbase + nb * 16 * DIN + k);
            acc[nb] = __builtin_amdgcn_mfma_f32_16x16x32_bf16(af, bf, acc[nb], 0, 0, 0);
        }
    }

    float sj0 = 0.f, sj1 = 0.f, sj2 = 0.f, sj3 = 0.f;
#pragma unroll
    for (int nb = 0; nb < 16; nb++) {
        int d = nb * 16 + m;
        float bias = rel_b[r * DOUT + d];
        float aw = attn_w[DOUT + d];
        float v0 = acc[nb][0] + bias;
        float v1 = acc[nb][1] + bias;
        float v2 = acc[nb][2] + bias;
        float v3 = acc[nb][3] + bias;
        ushort4 o;
        o.x = f2bf(v0); o.y = f2bf(v1); o.z = f2bf(v2); o.w = f2bf(v3);
        *(ushort4*)(featsT + (((b * R_ + r) * DOUT + d) * N_) + n0 + q * 4) = o;
        sj0 += v0 * aw; sj1 += v1 * aw; sj2 += v2 * aw; sj3 += v3 * aw;
    }
#pragma unroll
    for (int mk = 1; mk <= 8; mk <<= 1) {
        sj0 += __shfl_xor(sj0, mk, 64);
        sj1 += __shfl_xor(sj1, mk, 64);
        sj2 += __shfl_xor(sj2, mk, 64);
        sj3 += __shfl_xor(sj3, mk, 64);
    }
    if (m == 0) {
        ushort4 o;
        o.x = f2bf(__expf(sj0));
        o.y = f2bf(__expf(sj1));
        o.z = f2bf(__expf(sj2));
        o.w = f2bf(__expf(sj3));
        *(ushort4*)(ebf + (b * R_ + r) * N_ + n0 + q * 4) = o;
    }
}

// ---------------- k3: per-(b,r) masked softmax @ feats -> aggp[b,r,n,d] ----
// Barrier-free: B-fragments loaded directly from global (L1/L2-served; all 4
// waves in a block read the same tile). adj+e register-prefetched 1 step.
// grid 512 = (b,r,it), it = 64-row i-tile; 4 waves x 16 rows.
__global__ __launch_bounds__(256, 2) void k3_attn(const int* __restrict__ adj,
        const unsigned short* __restrict__ featsT, const unsigned short* __restrict__ ebf,
        float* __restrict__ aggp) {
    int bid = blockIdx.x;
    int it = bid & 15, r = (bid >> 4) & 3, b = bid >> 6;
    int t = threadIdx.x;
    int lane = t & 63, wave = t >> 6;
    int m = lane & 15, q = lane >> 4;
    int i0 = it * 64 + wave * 16;

    const int* adjbase = adj + (((b * R_ + r) * N_) + i0 + m) * (long)N_ + q * 8;
    const unsigned short* ebase = ebf + (b * R_ + r) * N_ + q * 8;
    const unsigned short* ftbase = featsT + ((long)((b * R_ + r) * DOUT)) * N_ + q * 8;

    f32x4 acc[16];
#pragma unroll
    for (int i = 0; i < 16; i++) acc[i] = (f32x4)0.0f;
    float l = 0.f;

    i32x4 a0 = *(const i32x4*)(adjbase);
    i32x4 a1 = *(const i32x4*)(adjbase + 4);
    bf16x8 eb = *(const bf16x8*)(ebase);

    for (int jb = 0; jb < N_; jb += 32) {
        int jn = (jb + 32) & (N_ - 1);  // wraps to 0 on last iter (discarded)
        i32x4 na0 = *(const i32x4*)(adjbase + jn);
        i32x4 na1 = *(const i32x4*)(adjbase + jn + 4);
        bf16x8 neb = *(const bf16x8*)(ebase + jn);

        int av[8] = {a0.x, a0.y, a0.z, a0.w, a1.x, a1.y, a1.z, a1.w};
        const int* ei = (const int*)&eb;
        bf16x8 af;
        int* afi = (int*)&af;
#pragma unroll
        for (int p = 0; p < 4; p++) {
            unsigned int mask = (av[2*p] ? 0xffffu : 0u) | (av[2*p+1] ? 0xffff0000u : 0u);
            int me = ei[p] & (int)mask;
            afi[p] = me;
            union { int i; float f; } lo, hi;
            lo.i = me << 16;
            hi.i = me & (int)0xffff0000u;
            l += lo.f + hi.f;
        }
#pragma unroll
        for (int nb = 0; nb < 16; nb++) {
            bf16x8 bfq = *(const bf16x8*)(ftbase + (long)(nb * 16 + m) * N_ + jb);
            acc[nb] = __builtin_amdgcn_mfma_f32_16x16x32_bf16(af, bfq, acc[nb], 0, 0, 0);
        }
        a0 = na0; a1 = na1; eb = neb;
    }

    // row-sum l: lanes {m, m+16, m+32, m+48} hold partial sums of row m
    l += __shfl_xor(l, 16, 64);
    l += __shfl_xor(l, 32, 64);
    float invl = (l > 0.f) ? 1.0f / l : 0.f;
    float invr[4];
#pragma unroll
    for (int reg = 0; reg < 4; reg++)
        invr[reg] = __shfl(invl, (lane >> 4) * 4 + reg, 64);

#pragma unroll
    for (int nb = 0; nb < 16; nb++) {
        int d = nb * 16 + m;
        float* outp = aggp + (((long)(b * R_ + r) * N_) + i0 + q * 4) * DOUT + d;
#pragma unroll
        for (int reg = 0; reg < 4; reg++)
            outp[reg * DOUT] = acc[nb][reg] * invr[reg];
    }
}

// ---------------- k4: out = sigmoid((sum_r aggp)·gw + gb) * sum_r aggp ------
__global__ __launch_bounds__(256) void k4_out(const float* __restrict__ aggp,
        const float* __restrict__ gate_w, const float* __restrict__ gate_b,
        float* __restrict__ out) {
    __shared__ float red[4];
    int bid = blockIdx.x;  // 8192 = b*1024 + n
    int n = bid & 1023, b = bid >> 10;
    int d = threadIdx.x;
    float s = 0.f;
#pragma unroll
    for (int r = 0; r < R_; r++)
        s += aggp[(((long)(b * R_ + r) * N_) + n) * DOUT + d];
    float v = s * gate_w[d];
#pragma unroll
    for (int off = 32; off; off >>= 1) v += __shfl_down(v, off, 64);
    int lane = d & 63, wave = d >> 6;
    if (lane == 0) red[wave] = v;
    __syncthreads();
    float tot = red[0] + red[1] + red[2] + red[3];
    float g = 1.f / (1.f + __expf(-(tot + gate_b[0])));
    out[((long)(b * N_ + n)) * DOUT + d] = g * s;
}

extern "C" void kernel_launch(void* const* d_in, const int* in_sizes, int n_in,
                              void* d_out, int out_size, void* d_ws, size_t ws_size,
                              hipStream_t stream) {
    const float* node   = (const float*)d_in[0];
    const int*   adj    = (const int*)d_in[1];
    const float* rel_w  = (const float*)d_in[2];
    const float* rel_b  = (const float*)d_in[3];
    const float* attn_w = (const float*)d_in[4];
    // d_in[5] = attn_b: cancels in softmax, unused
    const float* gate_w = (const float*)d_in[6];
    const float* gate_b = (const float*)d_in[7];
    float* out = (float*)d_out;

    char* ws = (char*)d_ws;
    unsigned short* relwb  = (unsigned short*)ws;                       // 524,288 B
    unsigned short* featsT = (unsigned short*)(ws + 524288);            // 16,777,216 B
    unsigned short* ebf    = (unsigned short*)(ws + 524288 + 16777216); // 65,536 B
    float*          aggp   = (float*)(ws + 524288 + 16777216 + 65536);  // 33,554,432 B

    k0_cvt_relw<<<256, 256, 0, stream>>>(rel_w, relwb);
    k1_proj<<<512, 256, 0, stream>>>(node, relwb, rel_b, attn_w, featsT, ebf);
    k3_attn<<<512, 256, 0, stream>>>(adj, featsT, ebf, aggp);
    k4_out<<<8192, 256, 0, stream>>>(aggp, gate_w, gate_b, out);
}